// Round 19
// baseline (199.484 us; speedup 1.0000x reference)
//
#include <hip/hip_runtime.h>
#include <hip/hip_bf16.h>
#include <stdint.h>

// ---------- helpers ----------
typedef __attribute__((ext_vector_type(8))) int v8i;
typedef __attribute__((ext_vector_type(4))) float f32x4;

__device__ __forceinline__ unsigned short f2bf(float f) {
  union { float f; unsigned int u; } v; v.f = f;
  unsigned int r = (v.u + 0x7fffu + ((v.u >> 16) & 1u)) >> 16;
  return (unsigned short)r;
}
__device__ __forceinline__ float bf2f(unsigned short h) {
  union { float f; unsigned int u; } v; v.u = ((unsigned int)h) << 16; return v.f;
}
// fp8 e4m3 (OCP) converts via HW packer
__device__ __forceinline__ unsigned char f2fp8(float f) {
  int r = __builtin_amdgcn_cvt_pk_fp8_f32(f, 0.f, 0, false);
  return (unsigned char)(r & 0xff);
}
__device__ __forceinline__ unsigned int f2fp8x4(float a, float b, float c, float d) {
  int r = __builtin_amdgcn_cvt_pk_fp8_f32(a, b, 0, false);
  r = __builtin_amdgcn_cvt_pk_fp8_f32(c, d, r, true);
  return (unsigned int)r;
}
// build v8i MFMA operand from two int4 register quads (static indices -> regs)
__device__ __forceinline__ v8i mkv8(int4 lo, int4 hi) {
  v8i r;
  r[0] = lo.x; r[1] = lo.y; r[2] = lo.z; r[3] = lo.w;
  r[4] = hi.x; r[5] = hi.y; r[6] = hi.z; r[7] = hi.w;
  return r;
}

// async global->LDS, 16B per lane; lds base wave-uniform, HW adds lane*16
__device__ __forceinline__ void async_copy16(const unsigned char* g, unsigned char* lds_base) {
  __builtin_amdgcn_global_load_lds(
      (const __attribute__((address_space(1))) unsigned int*)g,
      (__attribute__((address_space(3))) unsigned int*)lds_base,
      16, 0, 0);
}

// ---------- prep: fp32->fp8 converts (scale 16) + LayerNorm, one launch ----------
__global__ __launch_bounds__(256) void prep_kernel(const float* __restrict__ uvw,
                                                   unsigned int* __restrict__ uvw8, int n1_4,
                                                   const float* __restrict__ ow,
                                                   unsigned int* __restrict__ ow8, int n2_4,
                                                   int cvtB,
                                                   const float* __restrict__ x,
                                                   const float* __restrict__ gamma,
                                                   const float* __restrict__ beta,
                                                   unsigned int* __restrict__ h) {
  __shared__ float rs[4], rs2[4];
  const int t = threadIdx.x;
  if ((int)blockIdx.x < cvtB) {
    int i = blockIdx.x * 256 + t;
    const float* s; unsigned int* d; int idx;
    if (i < n1_4) { s = uvw; d = uvw8; idx = i; }
    else if (i < n1_4 + n2_4) { s = ow; d = ow8; idx = i - n1_4; }
    else return;
    float4 v = ((const float4*)s)[idx];
    d[idx] = f2fp8x4(v.x * 16.f, v.y * 16.f, v.z * 16.f, v.w * 16.f);
    return;
  }
  const int row = blockIdx.x - cvtB;
  const float4 v = ((const float4*)(x + (size_t)row * 1024))[t];
  float s  = v.x + v.y + v.z + v.w;
  float s2 = v.x*v.x + v.y*v.y + v.z*v.z + v.w*v.w;
#pragma unroll
  for (int o = 32; o > 0; o >>= 1) {
    s  += __shfl_down(s,  o, 64);
    s2 += __shfl_down(s2, o, 64);
  }
  const int wid = t >> 6;
  if ((t & 63) == 0) { rs[wid] = s; rs2[wid] = s2; }
  __syncthreads();
  const float S  = rs[0] + rs[1] + rs[2] + rs[3];
  const float S2 = rs2[0] + rs2[1] + rs2[2] + rs2[3];
  const float mu  = S * (1.f / 1024.f);
  const float inv = rsqrtf(S2 * (1.f / 1024.f) - mu * mu + 1e-5f);
  const float4 g = ((const float4*)gamma)[t];
  const float4 b = ((const float4*)beta)[t];
  h[row * 256 + t] = f2fp8x4((v.x - mu) * inv * g.x + b.x,
                             (v.y - mu) * inv * g.y + b.y,
                             (v.z - mu) * inv * g.z + b.z,
                             (v.w - mu) * inv * g.w + b.w);
}

// ---------- post: v-transpose + q/k projection, one launch ----------
__global__ __launch_bounds__(256) void post_kernel(const unsigned short* __restrict__ uv,
                                                   unsigned char* __restrict__ vT,
                                                   const float* __restrict__ qkw,
                                                   const float* __restrict__ qkb,
                                                   unsigned char* __restrict__ q,
                                                   unsigned char* __restrict__ k,
                                                   int n, int NU, int E, int S) {
  __shared__ unsigned short tile[64][68];
  const int t = threadIdx.x;
  if ((int)blockIdx.x >= 2048) {
    int i = ((int)blockIdx.x - 2048) * 256 + t;
    int nn = i / S, s = i - nn * S;
    float base = bf2f(uv[(size_t)nn * NU + 2 * E + s]);
    q[i] = f2fp8(16.f * (base * qkw[s]     + qkb[s]));
    k[i] = f2fp8(16.f * (base * qkw[S + s] + qkb[S + s]));
    return;
  }
  const int tm = ((int)blockIdx.x & 63) * 64;
  const int te = ((int)blockIdx.x >> 6) * 64;
  const int r  = t >> 4;
  const int c4 = (t & 15) * 4;
#pragma unroll
  for (int i = 0; i < 4; ++i) {
    int row = i * 16 + r;
    ushort4 v = *(const ushort4*)(uv + (size_t)(tm + row) * NU + E + te + c4);
    tile[row][c4 + 0] = v.x; tile[row][c4 + 1] = v.y;
    tile[row][c4 + 2] = v.z; tile[row][c4 + 3] = v.w;
  }
  __syncthreads();
#pragma unroll
  for (int i = 0; i < 4; ++i) {
    int erow = i * 16 + r;
    *(unsigned int*)(vT + (size_t)(te + erow) * n + tm + c4) =
        f2fp8x4(bf2f(tile[c4 + 0][erow]), bf2f(tile[c4 + 1][erow]),
                bf2f(tile[c4 + 2][erow]), bf2f(tile[c4 + 3][erow]));
  }
}

// ---------- fp8 MX GEMM: 128xBN tile, BK=128 bytes, THREADS/BN parametrized ----------
// R19 adds THREADS=256 variant for GEMM3: 4 waves 2Mx2N of 64x64 wave tiles
// (min LDS reads: 64KB/block-tile vs 96KB at 64x32) + NBUF=1 -> 32KB LDS ->
// 5 blocks/CU = 20 waves/CU. R13 proved the 64KB geometry but had only 8
// waves (37 B/cy); R12 has 16 waves but 96KB. This cell combines both.
// NBUF=1 uses the serial schedule { STAGE(t); vmcnt(0); barrier; READ+MFMA;
// barrier } — stage exposure is hidden by the 4 co-resident partner blocks
// (m114). Races: vmcnt(0)+barrier before reads; end-barrier separates
// reads(t) (retired before each wave's MFMA via compiler lgkm) from
// STAGE(t+1) overwrites.
// THREADS=512 paths (GEMM1/2/4) byte-identical to R18:
//   BN=128: 8 waves 2Mx4N, 64x32, NBUF=2 lookahead-1, 64KB -> 2 blocks/CU.
//   BN=64:  8 waves 4Mx2N, 32x32, NBUF=2, 48KB -> 3 blocks/CU.
// LDS: 16B-slot XOR swizzle (source slot16^(row&7), read (2kg)^r7/(2kg+1)^r7;
// rule #21 both-sides; numerically proven R6+).
// MFMA: v_mfma_scale_f32_16x16x128_f8f6f4, fp8/fp8, unit scales.
// EPI 0: silu(acc/16 + bias[col])      -> bf16 D   (A=h, B=16*uvw)
// EPI 1: 8*max(acc,0)^2               -> fp8 D    (= 2^26 * kernel_true)
// EPI 2: u * acc * 2^-2               -> fp8 D    (= 2^24 * ug_true)
// EPI 3: acc*2^-28 + bias[col] + X    -> f32 D
template <int EPI, int KTOT, int BN, int THREADS>
__global__ __launch_bounds__(THREADS, 4)
void gemm_f8(const unsigned char* __restrict__ A, int lda,
             const unsigned char* __restrict__ B, int ldb,
             void* __restrict__ D, int ldd,
             const float* __restrict__ bias,
             const unsigned short* __restrict__ U, int ldu,
             const float* __restrict__ X, int ldx) {
  constexpr int NT   = KTOT / 128;
  constexpr int NBUF = (NT == 1 || THREADS == 256) ? 1 : 2;
  constexpr int MM   = (BN == 128) ? 4 : 2;        // wave rows = MM*16
  constexpr int NN   = (THREADS == 256) ? 4 : 2;   // wave cols = NN*16
  constexpr int WM   = MM * 16;
  constexpr int WN   = NN * 16;
  constexpr int NWC  = BN / WN;                    // wave-columns per block
  constexpr int ROWS = THREADS / 8;                // rows per gload instr
  constexpr int AIT  = 128 / ROWS;
  constexpr int BIT  = BN / ROWS;

  __shared__ __align__(64) unsigned char As[NBUF][128 * 128];
  __shared__ __align__(64) unsigned char Bs[NBUF][BN * 128];

  const int tid  = threadIdx.x;
  const int wid  = tid >> 6;
  const int lane = tid & 63;
  const int bm = blockIdx.x * 128;
  const int bn = blockIdx.y * BN;
  const int wr = wid / NWC;
  const int wc = wid % NWC;
  const int frow = lane & 15;
  const int r7   = frow & 7;
  const int kg   = lane >> 4;
  const int s0   = ((2 * kg)     ^ r7) * 16;   // byte slot of K-window lo 16B
  const int s1   = ((2 * kg + 1) ^ r7) * 16;   // byte slot of K-window hi 16B

  // staging: per gload instr, THREADS threads cover ROWS rows x 128B (wave = 8 rows);
  // LDS[row][slot16] = G[row][slot16 ^ (row&7)] via pre-swizzled source
  const int srow  = tid >> 3;
  const int sslot = (tid & 7) ^ (srow & 7);
  const unsigned char* pA = A + (size_t)(bm + srow) * lda + sslot * 16;
  const unsigned char* pB = B + (size_t)(bn + srow) * ldb + sslot * 16;

#define STAGE(bufidx, k0)                                                                     \
  {                                                                                           \
    _Pragma("unroll")                                                                         \
    for (int i = 0; i < AIT; ++i)                                                             \
      async_copy16(pA + (size_t)(i * ROWS) * lda + (k0),                                      \
                   &As[bufidx][(i * ROWS + wid * 8) * 128]);                                  \
    _Pragma("unroll")                                                                         \
    for (int j = 0; j < BIT; ++j)                                                             \
      async_copy16(pB + (size_t)(j * ROWS) * ldb + (k0),                                      \
                   &Bs[bufidx][(j * ROWS + wid * 8) * 128]);                                  \
  }

#define READ_FRAGS(rbuf)                                                                      \
  {                                                                                           \
    _Pragma("unroll")                                                                         \
    for (int m = 0; m < MM; ++m) {                                                            \
      const int base = (wr * WM + m * 16 + frow) * 128;                                       \
      la[m] = *(const int4*)&As[rbuf][base + s0];                                             \
      ha[m] = *(const int4*)&As[rbuf][base + s1];                                             \
    }                                                                                         \
    _Pragma("unroll")                                                                         \
    for (int n = 0; n < NN; ++n) {                                                            \
      const int base = (wc * WN + n * 16 + frow) * 128;                                       \
      lb[n] = *(const int4*)&Bs[rbuf][base + s0];                                             \
      hb[n] = *(const int4*)&Bs[rbuf][base + s1];                                             \
    }                                                                                         \
  }

#define MFMA_ALL()                                                                            \
  {                                                                                           \
    _Pragma("unroll")                                                                         \
    for (int m = 0; m < MM; ++m) {                                                            \
      const v8i am = mkv8(la[m], ha[m]);                                                      \
      _Pragma("unroll")                                                                       \
      for (int n = 0; n < NN; ++n)                                                            \
        acc[m][n] = __builtin_amdgcn_mfma_scale_f32_16x16x128_f8f6f4(                         \
            am, mkv8(lb[n], hb[n]), acc[m][n], 0, 0, 0, 0x7f7f7f7f, 0, 0x7f7f7f7f);           \
    }                                                                                         \
  }

  f32x4 acc[MM][NN] = {};
  int4 la[MM], ha[MM], lb[NN], hb[NN];

  if constexpr (NT == 1) {
    STAGE(0, 0);
    asm volatile("s_waitcnt vmcnt(0)" ::: "memory");
    __builtin_amdgcn_s_barrier();
    READ_FRAGS(0);
    MFMA_ALL();
  } else if constexpr (NBUF == 1) {
    // serial schedule, stage exposure hidden by co-resident blocks (5/CU)
    for (int t = 0; t < NT; ++t) {
      STAGE(0, ((size_t)t) << 7);
      asm volatile("s_waitcnt vmcnt(0)" ::: "memory");
      __builtin_amdgcn_s_barrier();
      __builtin_amdgcn_sched_barrier(0);
      READ_FRAGS(0);
      __builtin_amdgcn_s_setprio(1);
      MFMA_ALL();
      __builtin_amdgcn_s_setprio(0);
      __builtin_amdgcn_sched_barrier(0);
      if (t + 1 < NT) {
        __builtin_amdgcn_s_barrier();   // all reads(t) done before STAGE(t+1)
        __builtin_amdgcn_sched_barrier(0);
      }
    }
  } else {
    STAGE(0, 0);
    asm volatile("s_waitcnt vmcnt(0)" ::: "memory");
    __builtin_amdgcn_s_barrier();
    __builtin_amdgcn_sched_barrier(0);
    for (int t = 0; t < NT; ++t) {
      if (t + 1 < NT) STAGE((t + 1) & 1, ((size_t)(t + 1)) << 7);
      READ_FRAGS(t & 1);
      __builtin_amdgcn_s_setprio(1);
      MFMA_ALL();
      __builtin_amdgcn_s_setprio(0);
      __builtin_amdgcn_sched_barrier(0);
      asm volatile("s_waitcnt vmcnt(0)" ::: "memory");
      __builtin_amdgcn_s_barrier();
      __builtin_amdgcn_sched_barrier(0);
    }
  }

#undef STAGE
#undef READ_FRAGS
#undef MFMA_ALL

  // epilogue (C/D layout: col=lane&15, row=(lane>>4)*4+r — shape-determined)
  const int rbase = (lane >> 4) * 4;
  const int cloc  = lane & 15;
#pragma unroll
  for (int m = 0; m < MM; ++m) {
#pragma unroll
    for (int n = 0; n < NN; ++n) {
      const int col = bn + wc * WN + n * 16 + cloc;
#pragma unroll
      for (int r = 0; r < 4; ++r) {
        const int row = bm + wr * WM + m * 16 + rbase + r;
        float v = acc[m][n][r];
        if constexpr (EPI == 0) {
          v = v * (1.f / 16.f) + bias[col];
          float sv = v / (1.f + __expf(-v));
          ((unsigned short*)D)[(size_t)row * ldd + col] = f2bf(sv);
        } else if constexpr (EPI == 1) {
          float z = fmaxf(v, 0.f);
          ((unsigned char*)D)[(size_t)row * ldd + col] = f2fp8(8.f * z * z);
        } else if constexpr (EPI == 2) {
          float u = bf2f(U[(size_t)row * ldu + col]);
          ((unsigned char*)D)[(size_t)row * ldd + col] = f2fp8(u * v * 0.25f);
        } else {
          ((float*)D)[(size_t)row * ldd + col] =
              v * (1.f / 268435456.f) + bias[col] + X[(size_t)row * ldx + col];
        }
      }
    }
  }
}

// ---------- launch ----------
extern "C" void kernel_launch(void* const* d_in, const int* in_sizes, int n_in,
                              void* d_out, int out_size, void* d_ws, size_t ws_size,
                              hipStream_t stream) {
  const float* x    = (const float*)d_in[0];
  const float* ln_g = (const float*)d_in[1];
  const float* ln_b = (const float*)d_in[2];
  const float* uv_w = (const float*)d_in[3];
  const float* uv_b = (const float*)d_in[4];
  const float* qk_w = (const float*)d_in[5];
  const float* qk_b = (const float*)d_in[6];
  const float* o_w  = (const float*)d_in[7];
  const float* o_b  = (const float*)d_in[8];
  float* out = (float*)d_out;

  const int H = 1024, E = 2048, S = 128;
  const int NU = 2 * E + S;          // 4224
  const int n = in_sizes[0] / H;     // 4096

  char* p = (char*)d_ws;
  unsigned char* h_f8   = (unsigned char*)p; p += (size_t)n * H;
  unsigned char* uvw_f8 = (unsigned char*)p; p += (size_t)NU * H;
  unsigned char* ow_f8  = (unsigned char*)p; p += (size_t)H * E;
  unsigned short* uv_bf = (unsigned short*)p; p += (size_t)n * NU * 2;
  unsigned char* q_f8   = (unsigned char*)p; p += (size_t)n * S;
  unsigned char* k_f8   = (unsigned char*)p; p += (size_t)n * S;
  unsigned char* vT_f8  = (unsigned char*)p; p += (size_t)E * n;
  unsigned char* ker_f8 = (unsigned char*)p; p += (size_t)n * n;
  unsigned char* ug_f8  = (unsigned char*)p; p += (size_t)n * E;

  const int n1_4 = NU * H / 4, n2_4 = H * E / 4;
  const int cvtB = (n1_4 + n2_4 + 255) / 256;

  // cvt(uv_w, o_w) + LayerNorm in one launch
  prep_kernel<<<cvtB + n, 256, 0, stream>>>(
      uv_w, (unsigned int*)uvw_f8, n1_4, o_w, (unsigned int*)ow_f8, n2_4, cvtB,
      x, ln_g, ln_b, (unsigned int*)h_f8);

  // uv = silu(h @ uv_w^T + uv_b)   M=4096 N=4224 K=1024 (NT=8) ; 1056 blocks, 2/CU
  gemm_f8<0, 1024, 128, 512><<<dim3(n / 128, NU / 128), 512, 0, stream>>>(
      h_f8, H, uvw_f8, H, uv_bf, NU, uv_b, nullptr, 0, nullptr, 0);

  // v-transpose + q/k projection in one launch (4096 blocks)
  post_kernel<<<4096, 256, 0, stream>>>(
      uv_bf, vT_f8, qk_w, qk_b, q_f8, k_f8, n, NU, E, S);

  // ker_f8 = 2^26 * relu(qk/sqrt(128))^2   M=N=4096 K=128 (NT=1) ; 1024 blocks
  gemm_f8<1, 128, 128, 512><<<dim3(n / 128, n / 128), 512, 0, stream>>>(
      q_f8, S, k_f8, S, ker_f8, n, nullptr, nullptr, 0, nullptr, 0);

  // ug_f8 = 2^24 * u * (kernel @ v)   M=4096 N=2048 K=4096 (NT=32) ;
  // 512 blocks @ 256thr, NBUF=1, 32KB LDS -> 5 blocks/CU, 20 waves/CU
  gemm_f8<2, 4096, 128, 256><<<dim3(n / 128, E / 128), 256, 0, stream>>>(
      ker_f8, n, vT_f8, n, ug_f8, E, nullptr, uv_bf, NU, nullptr, 0);

  // out = ug @ o_w^T + o_b + x   M=4096 N=1024 K=2048 (NT=16) ; BN=64 -> 512 blocks, 3/CU
  gemm_f8<3, 2048, 64, 512><<<dim3(n / 128, H / 64), 512, 0, stream>>>(
      ug_f8, E, ow_f8, E, out, H, o_b, nullptr, 0, x, H);
}

// Round 20
// 124.259 us; speedup vs baseline: 1.6054x; 1.6054x over previous
//
#include <hip/hip_runtime.h>
#include <hip/hip_bf16.h>
#include <stdint.h>

// ---------- helpers ----------
typedef __attribute__((ext_vector_type(8))) int v8i;
typedef __attribute__((ext_vector_type(4))) float f32x4;

__device__ __forceinline__ unsigned short f2bf(float f) {
  union { float f; unsigned int u; } v; v.f = f;
  unsigned int r = (v.u + 0x7fffu + ((v.u >> 16) & 1u)) >> 16;
  return (unsigned short)r;
}
__device__ __forceinline__ float bf2f(unsigned short h) {
  union { float f; unsigned int u; } v; v.u = ((unsigned int)h) << 16; return v.f;
}
// fp8 e4m3 (OCP) converts via HW packer
__device__ __forceinline__ unsigned char f2fp8(float f) {
  int r = __builtin_amdgcn_cvt_pk_fp8_f32(f, 0.f, 0, false);
  return (unsigned char)(r & 0xff);
}
__device__ __forceinline__ unsigned int f2fp8x4(float a, float b, float c, float d) {
  int r = __builtin_amdgcn_cvt_pk_fp8_f32(a, b, 0, false);
  r = __builtin_amdgcn_cvt_pk_fp8_f32(c, d, r, true);
  return (unsigned int)r;
}
// build v8i MFMA operand from two int4 register quads (static indices -> regs)
__device__ __forceinline__ v8i mkv8(int4 lo, int4 hi) {
  v8i r;
  r[0] = lo.x; r[1] = lo.y; r[2] = lo.z; r[3] = lo.w;
  r[4] = hi.x; r[5] = hi.y; r[6] = hi.z; r[7] = hi.w;
  return r;
}

// async global->LDS, 16B per lane; lds base wave-uniform, HW adds lane*16
__device__ __forceinline__ void async_copy16(const unsigned char* g, unsigned char* lds_base) {
  __builtin_amdgcn_global_load_lds(
      (const __attribute__((address_space(1))) unsigned int*)g,
      (__attribute__((address_space(3))) unsigned int*)lds_base,
      16, 0, 0);
}

// ---------- prep: fp32->fp8 converts (scale 16) + LayerNorm, one launch ----------
__global__ __launch_bounds__(256) void prep_kernel(const float* __restrict__ uvw,
                                                   unsigned int* __restrict__ uvw8, int n1_4,
                                                   const float* __restrict__ ow,
                                                   unsigned int* __restrict__ ow8, int n2_4,
                                                   int cvtB,
                                                   const float* __restrict__ x,
                                                   const float* __restrict__ gamma,
                                                   const float* __restrict__ beta,
                                                   unsigned int* __restrict__ h) {
  __shared__ float rs[4], rs2[4];
  const int t = threadIdx.x;
  if ((int)blockIdx.x < cvtB) {
    int i = blockIdx.x * 256 + t;
    const float* s; unsigned int* d; int idx;
    if (i < n1_4) { s = uvw; d = uvw8; idx = i; }
    else if (i < n1_4 + n2_4) { s = ow; d = ow8; idx = i - n1_4; }
    else return;
    float4 v = ((const float4*)s)[idx];
    d[idx] = f2fp8x4(v.x * 16.f, v.y * 16.f, v.z * 16.f, v.w * 16.f);
    return;
  }
  const int row = blockIdx.x - cvtB;
  const float4 v = ((const float4*)(x + (size_t)row * 1024))[t];
  float s  = v.x + v.y + v.z + v.w;
  float s2 = v.x*v.x + v.y*v.y + v.z*v.z + v.w*v.w;
#pragma unroll
  for (int o = 32; o > 0; o >>= 1) {
    s  += __shfl_down(s,  o, 64);
    s2 += __shfl_down(s2, o, 64);
  }
  const int wid = t >> 6;
  if ((t & 63) == 0) { rs[wid] = s; rs2[wid] = s2; }
  __syncthreads();
  const float S  = rs[0] + rs[1] + rs[2] + rs[3];
  const float S2 = rs2[0] + rs2[1] + rs2[2] + rs2[3];
  const float mu  = S * (1.f / 1024.f);
  const float inv = rsqrtf(S2 * (1.f / 1024.f) - mu * mu + 1e-5f);
  const float4 g = ((const float4*)gamma)[t];
  const float4 b = ((const float4*)beta)[t];
  h[row * 256 + t] = f2fp8x4((v.x - mu) * inv * g.x + b.x,
                             (v.y - mu) * inv * g.y + b.y,
                             (v.z - mu) * inv * g.z + b.z,
                             (v.w - mu) * inv * g.w + b.w);
}

// ---------- post: v-transpose + q/k projection, one launch ----------
__global__ __launch_bounds__(256) void post_kernel(const unsigned short* __restrict__ uv,
                                                   unsigned char* __restrict__ vT,
                                                   const float* __restrict__ qkw,
                                                   const float* __restrict__ qkb,
                                                   unsigned char* __restrict__ q,
                                                   unsigned char* __restrict__ k,
                                                   int n, int NU, int E, int S) {
  __shared__ unsigned short tile[64][68];
  const int t = threadIdx.x;
  if ((int)blockIdx.x >= 2048) {
    int i = ((int)blockIdx.x - 2048) * 256 + t;
    int nn = i / S, s = i - nn * S;
    float base = bf2f(uv[(size_t)nn * NU + 2 * E + s]);
    q[i] = f2fp8(16.f * (base * qkw[s]     + qkb[s]));
    k[i] = f2fp8(16.f * (base * qkw[S + s] + qkb[S + s]));
    return;
  }
  const int tm = ((int)blockIdx.x & 63) * 64;
  const int te = ((int)blockIdx.x >> 6) * 64;
  const int r  = t >> 4;
  const int c4 = (t & 15) * 4;
#pragma unroll
  for (int i = 0; i < 4; ++i) {
    int row = i * 16 + r;
    ushort4 v = *(const ushort4*)(uv + (size_t)(tm + row) * NU + E + te + c4);
    tile[row][c4 + 0] = v.x; tile[row][c4 + 1] = v.y;
    tile[row][c4 + 2] = v.z; tile[row][c4 + 3] = v.w;
  }
  __syncthreads();
#pragma unroll
  for (int i = 0; i < 4; ++i) {
    int erow = i * 16 + r;
    *(unsigned int*)(vT + (size_t)(te + erow) * n + tm + c4) =
        f2fp8x4(bf2f(tile[c4 + 0][erow]), bf2f(tile[c4 + 1][erow]),
                bf2f(tile[c4 + 2][erow]), bf2f(tile[c4 + 3][erow]));
  }
}

// ---------- fp8 MX GEMM: 128xBN tile, BK=128 bytes, THREADS/BN parametrized ----------
// R20 = R19 with the launch-bounds bug fixed: the 256-thread variant now
// declares (256, 2) — R13 proved this yields clean VGPR=88 allocation for
// the identical acc[4][4]+16-int4 register demand. R19's (256, 4) drove the
// allocator to a ~64-reg target -> 85MB/dispatch spill, MfmaUtil 10%.
// GEMM3 cell: 4 waves 2Mx2N of 64x64 wave tiles (min LDS reads, 64KB/tile)
// + NBUF=1 -> 32KB LDS -> 5 blocks/CU = 20 waves/CU (VGPR check:
// 5 waves/SIMD x 88 = 440 <= 512 pool). Serial schedule { STAGE(t);
// vmcnt(0); barrier; READ+MFMA; barrier } — stage exposure hidden by the 4
// co-resident partner blocks (m114). Races: vmcnt(0)+barrier before reads;
// end-barrier separates reads(t) (retired before each wave's last MFMA via
// compiler lgkm) from STAGE(t+1) overwrites.
// THREADS=512 paths (GEMM1/2/4) byte-identical to R18:
//   BN=128: 8 waves 2Mx4N, 64x32, NBUF=2 lookahead-1, 64KB -> 2 blocks/CU.
//   BN=64:  8 waves 4Mx2N, 32x32, NBUF=2, 48KB -> 3 blocks/CU.
// LDS: 16B-slot XOR swizzle (source slot16^(row&7), read (2kg)^r7/(2kg+1)^r7;
// rule #21 both-sides; numerically proven R6+).
// MFMA: v_mfma_scale_f32_16x16x128_f8f6f4, fp8/fp8, unit scales.
// EPI 0: silu(acc/16 + bias[col])      -> bf16 D   (A=h, B=16*uvw)
// EPI 1: 8*max(acc,0)^2               -> fp8 D    (= 2^26 * kernel_true)
// EPI 2: u * acc * 2^-2               -> fp8 D    (= 2^24 * ug_true)
// EPI 3: acc*2^-28 + bias[col] + X    -> f32 D
template <int EPI, int KTOT, int BN, int THREADS>
__global__ __launch_bounds__(THREADS, THREADS == 256 ? 2 : 4)
void gemm_f8(const unsigned char* __restrict__ A, int lda,
             const unsigned char* __restrict__ B, int ldb,
             void* __restrict__ D, int ldd,
             const float* __restrict__ bias,
             const unsigned short* __restrict__ U, int ldu,
             const float* __restrict__ X, int ldx) {
  constexpr int NT   = KTOT / 128;
  constexpr int NBUF = (NT == 1 || THREADS == 256) ? 1 : 2;
  constexpr int MM   = (BN == 128) ? 4 : 2;        // wave rows = MM*16
  constexpr int NN   = (THREADS == 256) ? 4 : 2;   // wave cols = NN*16
  constexpr int WM   = MM * 16;
  constexpr int WN   = NN * 16;
  constexpr int NWC  = BN / WN;                    // wave-columns per block
  constexpr int ROWS = THREADS / 8;                // rows per gload instr
  constexpr int AIT  = 128 / ROWS;
  constexpr int BIT  = BN / ROWS;

  __shared__ __align__(64) unsigned char As[NBUF][128 * 128];
  __shared__ __align__(64) unsigned char Bs[NBUF][BN * 128];

  const int tid  = threadIdx.x;
  const int wid  = tid >> 6;
  const int lane = tid & 63;
  const int bm = blockIdx.x * 128;
  const int bn = blockIdx.y * BN;
  const int wr = wid / NWC;
  const int wc = wid % NWC;
  const int frow = lane & 15;
  const int r7   = frow & 7;
  const int kg   = lane >> 4;
  const int s0   = ((2 * kg)     ^ r7) * 16;   // byte slot of K-window lo 16B
  const int s1   = ((2 * kg + 1) ^ r7) * 16;   // byte slot of K-window hi 16B

  // staging: per gload instr, THREADS threads cover ROWS rows x 128B (wave = 8 rows);
  // LDS[row][slot16] = G[row][slot16 ^ (row&7)] via pre-swizzled source
  const int srow  = tid >> 3;
  const int sslot = (tid & 7) ^ (srow & 7);
  const unsigned char* pA = A + (size_t)(bm + srow) * lda + sslot * 16;
  const unsigned char* pB = B + (size_t)(bn + srow) * ldb + sslot * 16;

#define STAGE(bufidx, k0)                                                                     \
  {                                                                                           \
    _Pragma("unroll")                                                                         \
    for (int i = 0; i < AIT; ++i)                                                             \
      async_copy16(pA + (size_t)(i * ROWS) * lda + (k0),                                      \
                   &As[bufidx][(i * ROWS + wid * 8) * 128]);                                  \
    _Pragma("unroll")                                                                         \
    for (int j = 0; j < BIT; ++j)                                                             \
      async_copy16(pB + (size_t)(j * ROWS) * ldb + (k0),                                      \
                   &Bs[bufidx][(j * ROWS + wid * 8) * 128]);                                  \
  }

#define READ_FRAGS(rbuf)                                                                      \
  {                                                                                           \
    _Pragma("unroll")                                                                         \
    for (int m = 0; m < MM; ++m) {                                                            \
      const int base = (wr * WM + m * 16 + frow) * 128;                                       \
      la[m] = *(const int4*)&As[rbuf][base + s0];                                             \
      ha[m] = *(const int4*)&As[rbuf][base + s1];                                             \
    }                                                                                         \
    _Pragma("unroll")                                                                         \
    for (int n = 0; n < NN; ++n) {                                                            \
      const int base = (wc * WN + n * 16 + frow) * 128;                                       \
      lb[n] = *(const int4*)&Bs[rbuf][base + s0];                                             \
      hb[n] = *(const int4*)&Bs[rbuf][base + s1];                                             \
    }                                                                                         \
  }

#define MFMA_ALL()                                                                            \
  {                                                                                           \
    _Pragma("unroll")                                                                         \
    for (int m = 0; m < MM; ++m) {                                                            \
      const v8i am = mkv8(la[m], ha[m]);                                                      \
      _Pragma("unroll")                                                                       \
      for (int n = 0; n < NN; ++n)                                                            \
        acc[m][n] = __builtin_amdgcn_mfma_scale_f32_16x16x128_f8f6f4(                         \
            am, mkv8(lb[n], hb[n]), acc[m][n], 0, 0, 0, 0x7f7f7f7f, 0, 0x7f7f7f7f);           \
    }                                                                                         \
  }

  f32x4 acc[MM][NN] = {};
  int4 la[MM], ha[MM], lb[NN], hb[NN];

  if constexpr (NT == 1) {
    STAGE(0, 0);
    asm volatile("s_waitcnt vmcnt(0)" ::: "memory");
    __builtin_amdgcn_s_barrier();
    READ_FRAGS(0);
    MFMA_ALL();
  } else if constexpr (NBUF == 1) {
    // serial schedule, stage exposure hidden by co-resident blocks (5/CU)
    for (int t = 0; t < NT; ++t) {
      STAGE(0, ((size_t)t) << 7);
      asm volatile("s_waitcnt vmcnt(0)" ::: "memory");
      __builtin_amdgcn_s_barrier();
      __builtin_amdgcn_sched_barrier(0);
      READ_FRAGS(0);
      __builtin_amdgcn_s_setprio(1);
      MFMA_ALL();
      __builtin_amdgcn_s_setprio(0);
      __builtin_amdgcn_sched_barrier(0);
      if (t + 1 < NT) {
        __builtin_amdgcn_s_barrier();   // all reads(t) done before STAGE(t+1)
        __builtin_amdgcn_sched_barrier(0);
      }
    }
  } else {
    STAGE(0, 0);
    asm volatile("s_waitcnt vmcnt(0)" ::: "memory");
    __builtin_amdgcn_s_barrier();
    __builtin_amdgcn_sched_barrier(0);
    for (int t = 0; t < NT; ++t) {
      if (t + 1 < NT) STAGE((t + 1) & 1, ((size_t)(t + 1)) << 7);
      READ_FRAGS(t & 1);
      __builtin_amdgcn_s_setprio(1);
      MFMA_ALL();
      __builtin_amdgcn_s_setprio(0);
      __builtin_amdgcn_sched_barrier(0);
      asm volatile("s_waitcnt vmcnt(0)" ::: "memory");
      __builtin_amdgcn_s_barrier();
      __builtin_amdgcn_sched_barrier(0);
    }
  }

#undef STAGE
#undef READ_FRAGS
#undef MFMA_ALL

  // epilogue (C/D layout: col=lane&15, row=(lane>>4)*4+r — shape-determined)
  const int rbase = (lane >> 4) * 4;
  const int cloc  = lane & 15;
#pragma unroll
  for (int m = 0; m < MM; ++m) {
#pragma unroll
    for (int n = 0; n < NN; ++n) {
      const int col = bn + wc * WN + n * 16 + cloc;
#pragma unroll
      for (int r = 0; r < 4; ++r) {
        const int row = bm + wr * WM + m * 16 + rbase + r;
        float v = acc[m][n][r];
        if constexpr (EPI == 0) {
          v = v * (1.f / 16.f) + bias[col];
          float sv = v / (1.f + __expf(-v));
          ((unsigned short*)D)[(size_t)row * ldd + col] = f2bf(sv);
        } else if constexpr (EPI == 1) {
          float z = fmaxf(v, 0.f);
          ((unsigned char*)D)[(size_t)row * ldd + col] = f2fp8(8.f * z * z);
        } else if constexpr (EPI == 2) {
          float u = bf2f(U[(size_t)row * ldu + col]);
          ((unsigned char*)D)[(size_t)row * ldd + col] = f2fp8(u * v * 0.25f);
        } else {
          ((float*)D)[(size_t)row * ldd + col] =
              v * (1.f / 268435456.f) + bias[col] + X[(size_t)row * ldx + col];
        }
      }
    }
  }
}

// ---------- launch ----------
extern "C" void kernel_launch(void* const* d_in, const int* in_sizes, int n_in,
                              void* d_out, int out_size, void* d_ws, size_t ws_size,
                              hipStream_t stream) {
  const float* x    = (const float*)d_in[0];
  const float* ln_g = (const float*)d_in[1];
  const float* ln_b = (const float*)d_in[2];
  const float* uv_w = (const float*)d_in[3];
  const float* uv_b = (const float*)d_in[4];
  const float* qk_w = (const float*)d_in[5];
  const float* qk_b = (const float*)d_in[6];
  const float* o_w  = (const float*)d_in[7];
  const float* o_b  = (const float*)d_in[8];
  float* out = (float*)d_out;

  const int H = 1024, E = 2048, S = 128;
  const int NU = 2 * E + S;          // 4224
  const int n = in_sizes[0] / H;     // 4096

  char* p = (char*)d_ws;
  unsigned char* h_f8   = (unsigned char*)p; p += (size_t)n * H;
  unsigned char* uvw_f8 = (unsigned char*)p; p += (size_t)NU * H;
  unsigned char* ow_f8  = (unsigned char*)p; p += (size_t)H * E;
  unsigned short* uv_bf = (unsigned short*)p; p += (size_t)n * NU * 2;
  unsigned char* q_f8   = (unsigned char*)p; p += (size_t)n * S;
  unsigned char* k_f8   = (unsigned char*)p; p += (size_t)n * S;
  unsigned char* vT_f8  = (unsigned char*)p; p += (size_t)E * n;
  unsigned char* ker_f8 = (unsigned char*)p; p += (size_t)n * n;
  unsigned char* ug_f8  = (unsigned char*)p; p += (size_t)n * E;

  const int n1_4 = NU * H / 4, n2_4 = H * E / 4;
  const int cvtB = (n1_4 + n2_4 + 255) / 256;

  // cvt(uv_w, o_w) + LayerNorm in one launch
  prep_kernel<<<cvtB + n, 256, 0, stream>>>(
      uv_w, (unsigned int*)uvw_f8, n1_4, o_w, (unsigned int*)ow_f8, n2_4, cvtB,
      x, ln_g, ln_b, (unsigned int*)h_f8);

  // uv = silu(h @ uv_w^T + uv_b)   M=4096 N=4224 K=1024 (NT=8) ; 1056 blocks, 2/CU
  gemm_f8<0, 1024, 128, 512><<<dim3(n / 128, NU / 128), 512, 0, stream>>>(
      h_f8, H, uvw_f8, H, uv_bf, NU, uv_b, nullptr, 0, nullptr, 0);

  // v-transpose + q/k projection in one launch (4096 blocks)
  post_kernel<<<4096, 256, 0, stream>>>(
      uv_bf, vT_f8, qk_w, qk_b, q_f8, k_f8, n, NU, E, S);

  // ker_f8 = 2^26 * relu(qk/sqrt(128))^2   M=N=4096 K=128 (NT=1) ; 1024 blocks
  gemm_f8<1, 128, 128, 512><<<dim3(n / 128, n / 128), 512, 0, stream>>>(
      q_f8, S, k_f8, S, ker_f8, n, nullptr, nullptr, 0, nullptr, 0);

  // ug_f8 = 2^24 * u * (kernel @ v)   M=4096 N=2048 K=4096 (NT=32) ;
  // 512 blocks @ 256thr, NBUF=1, 32KB LDS -> 5 blocks/CU, 20 waves/CU
  gemm_f8<2, 4096, 128, 256><<<dim3(n / 128, E / 128), 256, 0, stream>>>(
      ker_f8, n, vT_f8, n, ug_f8, E, nullptr, uv_bf, NU, nullptr, 0);

  // out = ug @ o_w^T + o_b + x   M=4096 N=1024 K=2048 (NT=16) ; BN=64 -> 512 blocks, 3/CU
  gemm_f8<3, 2048, 64, 512><<<dim3(n / 128, H / 64), 512, 0, stream>>>(
      ug_f8, E, ow_f8, E, out, H, o_b, nullptr, 0, x, H);
}

// Round 21
// 122.411 us; speedup vs baseline: 1.6296x; 1.0151x over previous
//
#include <hip/hip_runtime.h>
#include <hip/hip_bf16.h>
#include <stdint.h>

// ---------- helpers ----------
typedef __attribute__((ext_vector_type(8))) int v8i;
typedef __attribute__((ext_vector_type(4))) float f32x4;

__device__ __forceinline__ unsigned short f2bf(float f) {
  union { float f; unsigned int u; } v; v.f = f;
  unsigned int r = (v.u + 0x7fffu + ((v.u >> 16) & 1u)) >> 16;
  return (unsigned short)r;
}
__device__ __forceinline__ float bf2f(unsigned short h) {
  union { float f; unsigned int u; } v; v.u = ((unsigned int)h) << 16; return v.f;
}
// fp8 e4m3 (OCP) converts via HW packer
__device__ __forceinline__ unsigned char f2fp8(float f) {
  int r = __builtin_amdgcn_cvt_pk_fp8_f32(f, 0.f, 0, false);
  return (unsigned char)(r & 0xff);
}
__device__ __forceinline__ unsigned int f2fp8x4(float a, float b, float c, float d) {
  int r = __builtin_amdgcn_cvt_pk_fp8_f32(a, b, 0, false);
  r = __builtin_amdgcn_cvt_pk_fp8_f32(c, d, r, true);
  return (unsigned int)r;
}
// build v8i MFMA operand from two int4 register quads (static indices -> regs)
__device__ __forceinline__ v8i mkv8(int4 lo, int4 hi) {
  v8i r;
  r[0] = lo.x; r[1] = lo.y; r[2] = lo.z; r[3] = lo.w;
  r[4] = hi.x; r[5] = hi.y; r[6] = hi.z; r[7] = hi.w;
  return r;
}

// async global->LDS, 16B per lane; lds base wave-uniform, HW adds lane*16
__device__ __forceinline__ void async_copy16(const unsigned char* g, unsigned char* lds_base) {
  __builtin_amdgcn_global_load_lds(
      (const __attribute__((address_space(1))) unsigned int*)g,
      (__attribute__((address_space(3))) unsigned int*)lds_base,
      16, 0, 0);
}

// ---------- prep: fp32->fp8 converts (scale 16) + LayerNorm, one launch ----------
__global__ __launch_bounds__(256) void prep_kernel(const float* __restrict__ uvw,
                                                   unsigned int* __restrict__ uvw8, int n1_4,
                                                   const float* __restrict__ ow,
                                                   unsigned int* __restrict__ ow8, int n2_4,
                                                   int cvtB,
                                                   const float* __restrict__ x,
                                                   const float* __restrict__ gamma,
                                                   const float* __restrict__ beta,
                                                   unsigned int* __restrict__ h) {
  __shared__ float rs[4], rs2[4];
  const int t = threadIdx.x;
  if ((int)blockIdx.x < cvtB) {
    int i = blockIdx.x * 256 + t;
    const float* s; unsigned int* d; int idx;
    if (i < n1_4) { s = uvw; d = uvw8; idx = i; }
    else if (i < n1_4 + n2_4) { s = ow; d = ow8; idx = i - n1_4; }
    else return;
    float4 v = ((const float4*)s)[idx];
    d[idx] = f2fp8x4(v.x * 16.f, v.y * 16.f, v.z * 16.f, v.w * 16.f);
    return;
  }
  const int row = blockIdx.x - cvtB;
  const float4 v = ((const float4*)(x + (size_t)row * 1024))[t];
  float s  = v.x + v.y + v.z + v.w;
  float s2 = v.x*v.x + v.y*v.y + v.z*v.z + v.w*v.w;
#pragma unroll
  for (int o = 32; o > 0; o >>= 1) {
    s  += __shfl_down(s,  o, 64);
    s2 += __shfl_down(s2, o, 64);
  }
  const int wid = t >> 6;
  if ((t & 63) == 0) { rs[wid] = s; rs2[wid] = s2; }
  __syncthreads();
  const float S  = rs[0] + rs[1] + rs[2] + rs[3];
  const float S2 = rs2[0] + rs2[1] + rs2[2] + rs2[3];
  const float mu  = S * (1.f / 1024.f);
  const float inv = rsqrtf(S2 * (1.f / 1024.f) - mu * mu + 1e-5f);
  const float4 g = ((const float4*)gamma)[t];
  const float4 b = ((const float4*)beta)[t];
  h[row * 256 + t] = f2fp8x4((v.x - mu) * inv * g.x + b.x,
                             (v.y - mu) * inv * g.y + b.y,
                             (v.z - mu) * inv * g.z + b.z,
                             (v.w - mu) * inv * g.w + b.w);
}

// ---------- post: v-transpose + q/k projection, one launch ----------
__global__ __launch_bounds__(256) void post_kernel(const unsigned short* __restrict__ uv,
                                                   unsigned char* __restrict__ vT,
                                                   const float* __restrict__ qkw,
                                                   const float* __restrict__ qkb,
                                                   unsigned char* __restrict__ q,
                                                   unsigned char* __restrict__ k,
                                                   int n, int NU, int E, int S) {
  __shared__ unsigned short tile[64][68];
  const int t = threadIdx.x;
  if ((int)blockIdx.x >= 2048) {
    int i = ((int)blockIdx.x - 2048) * 256 + t;
    int nn = i / S, s = i - nn * S;
    float base = bf2f(uv[(size_t)nn * NU + 2 * E + s]);
    q[i] = f2fp8(16.f * (base * qkw[s]     + qkb[s]));
    k[i] = f2fp8(16.f * (base * qkw[S + s] + qkb[S + s]));
    return;
  }
  const int tm = ((int)blockIdx.x & 63) * 64;
  const int te = ((int)blockIdx.x >> 6) * 64;
  const int r  = t >> 4;
  const int c4 = (t & 15) * 4;
#pragma unroll
  for (int i = 0; i < 4; ++i) {
    int row = i * 16 + r;
    ushort4 v = *(const ushort4*)(uv + (size_t)(tm + row) * NU + E + te + c4);
    tile[row][c4 + 0] = v.x; tile[row][c4 + 1] = v.y;
    tile[row][c4 + 2] = v.z; tile[row][c4 + 3] = v.w;
  }
  __syncthreads();
#pragma unroll
  for (int i = 0; i < 4; ++i) {
    int erow = i * 16 + r;
    *(unsigned int*)(vT + (size_t)(te + erow) * n + tm + c4) =
        f2fp8x4(bf2f(tile[c4 + 0][erow]), bf2f(tile[c4 + 1][erow]),
                bf2f(tile[c4 + 2][erow]), bf2f(tile[c4 + 3][erow]));
  }
}

// ---------- fp8 MX GEMM: 128xBN tile, BK=128 bytes, NBUF=2 ----------
// R21 = R18 restored (session best, 122.6us). GEMM3 back to the proven
// 512-thr BN=128 lookahead-1 config (43.2us). R19/R20 probes showed the
// 256-thr 64x64-wave-tile cell cannot beat it: GEMM3's 512-block grid caps
// residency at 2 blocks/CU, so the 20-wave occupancy the LDS-BW model
// needs is unreachable (measured 45.3us vs 43.2).
// Template variants (all proven):
//   BN=128, 512thr: 8 waves 2Mx4N, 64x32 tiles, NBUF=2 lookahead-1,
//     64KB LDS -> 2 blocks/CU (GEMM1/2/3).
//   BN=64, 512thr:  8 waves 4Mx2N, 32x32 tiles, NBUF=2, 48KB -> 3/CU (GEMM4).
// Schedule per K-tile: { STAGE(t+1 -> wb) ; READ+MFMA(rb) ; vmcnt(0) ;
// barrier }. Races: reads(rb=t&1) need stage(t) retired — prior iter ended
// vmcnt(0)+barrier; stage(t+1) writes wb=(t+1)&1, read last at t-1, its
// ds_reads all consumed by MFMAs (compiler lgkm) before that iter's barrier.
// LDS: 16B-slot XOR swizzle (source slot16^(row&7), read (2kg)^r7/(2kg+1)^r7;
// rule #21 both-sides; numerically proven R6+).
// MFMA: v_mfma_scale_f32_16x16x128_f8f6f4, fp8/fp8, unit scales.
// EPI 0: silu(acc/16 + bias[col])      -> bf16 D   (A=h, B=16*uvw)
// EPI 1: 8*max(acc,0)^2               -> fp8 D    (= 2^26 * kernel_true)
// EPI 2: u * acc * 2^-2               -> fp8 D    (= 2^24 * ug_true)
// EPI 3: acc*2^-28 + bias[col] + X    -> f32 D
template <int EPI, int KTOT, int BN>
__global__ __launch_bounds__(512, 4)
void gemm_f8(const unsigned char* __restrict__ A, int lda,
             const unsigned char* __restrict__ B, int ldb,
             void* __restrict__ D, int ldd,
             const float* __restrict__ bias,
             const unsigned short* __restrict__ U, int ldu,
             const float* __restrict__ X, int ldx) {
  constexpr int NT   = KTOT / 128;
  constexpr int NBUF = (NT == 1) ? 1 : 2;
  constexpr int MM   = (BN == 128) ? 4 : 2;   // A m-repeats (wave rows = MM*16)
  constexpr int NN   = 2;
  constexpr int WM   = MM * 16;               // wave row span
  constexpr int BIT  = BN / 64;               // B gloads per tile

  __shared__ __align__(64) unsigned char As[NBUF][128 * 128];
  __shared__ __align__(64) unsigned char Bs[NBUF][BN * 128];

  const int tid  = threadIdx.x;
  const int wid  = tid >> 6;
  const int lane = tid & 63;
  const int bm = blockIdx.x * 128;
  const int bn = blockIdx.y * BN;
  const int wr = (BN == 128) ? (wid >> 2) : (wid >> 1);
  const int wc = (BN == 128) ? (wid & 3)  : (wid & 1);
  const int frow = lane & 15;
  const int r7   = frow & 7;
  const int kg   = lane >> 4;
  const int s0   = ((2 * kg)     ^ r7) * 16;   // byte slot of K-window lo 16B
  const int s1   = ((2 * kg + 1) ^ r7) * 16;   // byte slot of K-window hi 16B

  // staging: per gload instr, 512 threads cover 64 rows x 128B (wave = 8 rows);
  // LDS[row][slot16] = G[row][slot16 ^ (row&7)] via pre-swizzled source
  const int srow  = tid >> 3;
  const int sslot = (tid & 7) ^ (srow & 7);
  const unsigned char* pA = A + (size_t)(bm + srow) * lda + sslot * 16;
  const unsigned char* pB = B + (size_t)(bn + srow) * ldb + sslot * 16;

#define STAGE(bufidx, k0)                                                                     \
  {                                                                                           \
    _Pragma("unroll")                                                                         \
    for (int i = 0; i < 2; ++i)                                                               \
      async_copy16(pA + (size_t)(i * 64) * lda + (k0), &As[bufidx][(i * 64 + wid * 8) * 128]);\
    _Pragma("unroll")                                                                         \
    for (int j = 0; j < BIT; ++j)                                                             \
      async_copy16(pB + (size_t)(j * 64) * ldb + (k0), &Bs[bufidx][(j * 64 + wid * 8) * 128]);\
  }

#define READ_FRAGS(rbuf)                                                                      \
  {                                                                                           \
    _Pragma("unroll")                                                                         \
    for (int m = 0; m < MM; ++m) {                                                            \
      const int base = (wr * WM + m * 16 + frow) * 128;                                       \
      la[m] = *(const int4*)&As[rbuf][base + s0];                                             \
      ha[m] = *(const int4*)&As[rbuf][base + s1];                                             \
    }                                                                                         \
    _Pragma("unroll")                                                                         \
    for (int n = 0; n < NN; ++n) {                                                            \
      const int base = (wc * 32 + n * 16 + frow) * 128;                                       \
      lb[n] = *(const int4*)&Bs[rbuf][base + s0];                                             \
      hb[n] = *(const int4*)&Bs[rbuf][base + s1];                                             \
    }                                                                                         \
  }

#define MFMA_ALL()                                                                            \
  {                                                                                           \
    _Pragma("unroll")                                                                         \
    for (int m = 0; m < MM; ++m) {                                                            \
      const v8i am = mkv8(la[m], ha[m]);                                                      \
      _Pragma("unroll")                                                                       \
      for (int n = 0; n < NN; ++n)                                                            \
        acc[m][n] = __builtin_amdgcn_mfma_scale_f32_16x16x128_f8f6f4(                         \
            am, mkv8(lb[n], hb[n]), acc[m][n], 0, 0, 0, 0x7f7f7f7f, 0, 0x7f7f7f7f);           \
    }                                                                                         \
  }

  f32x4 acc[MM][NN] = {};
  int4 la[MM], ha[MM], lb[NN], hb[NN];

  if constexpr (NT == 1) {
    STAGE(0, 0);
    asm volatile("s_waitcnt vmcnt(0)" ::: "memory");
    __builtin_amdgcn_s_barrier();
    READ_FRAGS(0);
    MFMA_ALL();
  } else {
    STAGE(0, 0);
    asm volatile("s_waitcnt vmcnt(0)" ::: "memory");
    __builtin_amdgcn_s_barrier();
    __builtin_amdgcn_sched_barrier(0);
    for (int t = 0; t < NT; ++t) {
      if (t + 1 < NT) STAGE((t + 1) & 1, ((size_t)(t + 1)) << 7);
      READ_FRAGS(t & 1);
      __builtin_amdgcn_s_setprio(1);
      MFMA_ALL();
      __builtin_amdgcn_s_setprio(0);
      __builtin_amdgcn_sched_barrier(0);
      asm volatile("s_waitcnt vmcnt(0)" ::: "memory");
      __builtin_amdgcn_s_barrier();
      __builtin_amdgcn_sched_barrier(0);
    }
  }

#undef STAGE
#undef READ_FRAGS
#undef MFMA_ALL

  // epilogue (C/D layout: col=lane&15, row=(lane>>4)*4+r — shape-determined)
  const int rbase = (lane >> 4) * 4;
  const int cloc  = lane & 15;
#pragma unroll
  for (int m = 0; m < MM; ++m) {
#pragma unroll
    for (int n = 0; n < NN; ++n) {
      const int col = bn + wc * 32 + n * 16 + cloc;
#pragma unroll
      for (int r = 0; r < 4; ++r) {
        const int row = bm + wr * WM + m * 16 + rbase + r;
        float v = acc[m][n][r];
        if constexpr (EPI == 0) {
          v = v * (1.f / 16.f) + bias[col];
          float sv = v / (1.f + __expf(-v));
          ((unsigned short*)D)[(size_t)row * ldd + col] = f2bf(sv);
        } else if constexpr (EPI == 1) {
          float z = fmaxf(v, 0.f);
          ((unsigned char*)D)[(size_t)row * ldd + col] = f2fp8(8.f * z * z);
        } else if constexpr (EPI == 2) {
          float u = bf2f(U[(size_t)row * ldu + col]);
          ((unsigned char*)D)[(size_t)row * ldd + col] = f2fp8(u * v * 0.25f);
        } else {
          ((float*)D)[(size_t)row * ldd + col] =
              v * (1.f / 268435456.f) + bias[col] + X[(size_t)row * ldx + col];
        }
      }
    }
  }
}

// ---------- launch ----------
extern "C" void kernel_launch(void* const* d_in, const int* in_sizes, int n_in,
                              void* d_out, int out_size, void* d_ws, size_t ws_size,
                              hipStream_t stream) {
  const float* x    = (const float*)d_in[0];
  const float* ln_g = (const float*)d_in[1];
  const float* ln_b = (const float*)d_in[2];
  const float* uv_w = (const float*)d_in[3];
  const float* uv_b = (const float*)d_in[4];
  const float* qk_w = (const float*)d_in[5];
  const float* qk_b = (const float*)d_in[6];
  const float* o_w  = (const float*)d_in[7];
  const float* o_b  = (const float*)d_in[8];
  float* out = (float*)d_out;

  const int H = 1024, E = 2048, S = 128;
  const int NU = 2 * E + S;          // 4224
  const int n = in_sizes[0] / H;     // 4096

  char* p = (char*)d_ws;
  unsigned char* h_f8   = (unsigned char*)p; p += (size_t)n * H;
  unsigned char* uvw_f8 = (unsigned char*)p; p += (size_t)NU * H;
  unsigned char* ow_f8  = (unsigned char*)p; p += (size_t)H * E;
  unsigned short* uv_bf = (unsigned short*)p; p += (size_t)n * NU * 2;
  unsigned char* q_f8   = (unsigned char*)p; p += (size_t)n * S;
  unsigned char* k_f8   = (unsigned char*)p; p += (size_t)n * S;
  unsigned char* vT_f8  = (unsigned char*)p; p += (size_t)E * n;
  unsigned char* ker_f8 = (unsigned char*)p; p += (size_t)n * n;
  unsigned char* ug_f8  = (unsigned char*)p; p += (size_t)n * E;

  const int n1_4 = NU * H / 4, n2_4 = H * E / 4;
  const int cvtB = (n1_4 + n2_4 + 255) / 256;

  // cvt(uv_w, o_w) + LayerNorm in one launch
  prep_kernel<<<cvtB + n, 256, 0, stream>>>(
      uv_w, (unsigned int*)uvw_f8, n1_4, o_w, (unsigned int*)ow_f8, n2_4, cvtB,
      x, ln_g, ln_b, (unsigned int*)h_f8);

  // uv = silu(h @ uv_w^T + uv_b)   M=4096 N=4224 K=1024 (NT=8) ; 1056 blocks, 2/CU
  gemm_f8<0, 1024, 128><<<dim3(n / 128, NU / 128), 512, 0, stream>>>(
      h_f8, H, uvw_f8, H, uv_bf, NU, uv_b, nullptr, 0, nullptr, 0);

  // v-transpose + q/k projection in one launch (4096 blocks)
  post_kernel<<<4096, 256, 0, stream>>>(
      uv_bf, vT_f8, qk_w, qk_b, q_f8, k_f8, n, NU, E, S);

  // ker_f8 = 2^26 * relu(qk/sqrt(128))^2   M=N=4096 K=128 (NT=1) ; 1024 blocks
  gemm_f8<1, 128, 128><<<dim3(n / 128, n / 128), 512, 0, stream>>>(
      q_f8, S, k_f8, S, ker_f8, n, nullptr, nullptr, 0, nullptr, 0);

  // ug_f8 = 2^24 * u * (kernel @ v)   M=4096 N=2048 K=4096 (NT=32) ; 512 blocks, 2/CU
  gemm_f8<2, 4096, 128><<<dim3(n / 128, E / 128), 512, 0, stream>>>(
      ker_f8, n, vT_f8, n, ug_f8, E, nullptr, uv_bf, NU, nullptr, 0);

  // out = ug @ o_w^T + o_b + x   M=4096 N=1024 K=2048 (NT=16) ; BN=64 -> 512 blocks, 3/CU
  gemm_f8<3, 2048, 64><<<dim3(n / 128, H / 64), 512, 0, stream>>>(
      ug_f8, E, ow_f8, E, out, H, o_b, nullptr, 0, x, H);
}